// Round 1
// baseline (667.357 us; speedup 1.0000x reference)
//
#include <hip/hip_runtime.h>
#include <math.h>

#define B_ 64
#define T_ 2048
#define DL 1024
#define DE 512
#define DA 128
#define NF 32
#define KW 31
#define PADW 15

#define TT 128      // t-tile per block in energy kernel
#define KC 32       // K chunk
#define LDW 136     // padded leading dim for LDS tiles (128 + 8)

// ---------------- Kernel 1: q = query @ Wq.T + bq  ([B,128]) ----------------
__global__ __launch_bounds__(128) void q_kernel(const float* __restrict__ query,
                                                const float* __restrict__ Wq,
                                                const float* __restrict__ bq,
                                                float* __restrict__ qbuf) {
    int b = blockIdx.x;
    int a = threadIdx.x;
    __shared__ __align__(16) float qs[DL];
    for (int i = threadIdx.x; i < DL; i += 128) qs[i] = query[(size_t)b * DL + i];
    __syncthreads();
    const float* wrow = Wq + (size_t)a * DL;
    float acc = 0.f;
#pragma unroll 8
    for (int i = 0; i < DL; i += 4) {
        float4 w = *(const float4*)(wrow + i);
        float4 q4 = *(const float4*)(qs + i);
        acc += w.x * q4.x + w.y * q4.y + w.z * q4.z + w.w * q4.w;
    }
    qbuf[(size_t)b * DA + a] = acc + bq[a];
}

// ---------------- Kernel 2: energies e[b,t] ----------------
// Per block: one b, 128 t's. Computes:
//   acc[t][a] = sum_k mem[b,t,k]*Wm[a,k]  (K=512, fp32 LDS GEMM)
//            += sum_f conv[b,f,t]*Wloc[a,f]  (conv computed in-block)
//   e[b,t] = bv + sum_a Wv[a]*tanh(acc[t][a] + q[b,a] + bm[a])
__global__ __launch_bounds__(256) void energy_kernel(
    const float* __restrict__ mem,    // [B,T,512]
    const float* __restrict__ attw,   // [B,2,T]
    const float* __restrict__ Wm,     // [128,512]
    const float* __restrict__ bm,     // [128]
    const float* __restrict__ Wconv,  // [32,2,31]
    const float* __restrict__ Wloc,   // [128,32]
    const float* __restrict__ Wv,     // [128]
    const float* __restrict__ bv,     // [1]
    const float* __restrict__ qbuf,   // [B,128]
    float* __restrict__ e_out)        // [B,T]
{
    __shared__ __align__(16) float scratch[2 * KC * LDW];  // 8704 floats: As/Bs (and phase-1 staging)
    __shared__ __align__(16) float convT[NF * LDW];        // conv, [f][t] layout
    __shared__ float qb_s[DA];
    __shared__ float wv_s[DA];

    const int tid = threadIdx.x;
    const int b = blockIdx.y;
    const int t0 = blockIdx.x * TT;
    const int tx = tid & 15;   // a-group: a = tx*8 + j
    const int ty = tid >> 4;   // t-group: t = ty*8 + i

    if (tid < DA) {
        qb_s[tid] = qbuf[(size_t)b * DA + tid] + bm[tid];
        wv_s[tid] = Wv[tid];
    }

    // ---- phase 1: stage attention_weights_cat slice + Wconv in scratch ----
    float* attw_s  = scratch;         // [2][160], j -> global t0-15+j, 158 valid
    float* wconv_s = scratch + 320;   // [32][64], r = c*31+k
    for (int i = tid; i < 2 * (TT + KW - 1); i += 256) {
        int c = i / (TT + KW - 1);
        int j = i % (TT + KW - 1);
        int t = t0 - PADW + j;
        attw_s[c * 160 + j] = (t >= 0 && t < T_) ? attw[((size_t)b * 2 + c) * T_ + t] : 0.f;
    }
    for (int i = tid; i < NF * 2 * KW; i += 256) {
        int f = i / (2 * KW);
        int r = i % (2 * KW);
        wconv_s[f * 64 + r] = Wconv[i];
    }
    __syncthreads();

    // ---- phase 2: conv (same padding) -> convT[f][t] ----
    for (int i = tid; i < TT * NF; i += 256) {
        int t = i >> 5;
        int f = i & 31;
        const float* w0 = wconv_s + f * 64;
        const float* a0 = attw_s + t;         // c=0, offsets t..t+30
        const float* a1 = attw_s + 160 + t;   // c=1
        float s = 0.f;
#pragma unroll
        for (int k = 0; k < KW; ++k) s += w0[k] * a0[k] + w0[31 + k] * a1[k];
        convT[f * LDW + t] = s;
    }
    __syncthreads();  // also frees scratch for GEMM tiles

    float acc[8][8];
#pragma unroll
    for (int i = 0; i < 8; ++i)
#pragma unroll
        for (int j = 0; j < 8; ++j) acc[i][j] = 0.f;

    float* As = scratch;             // [KC][LDW]: k-major, t inner
    float* Bs = scratch + KC * LDW;  // [KC][LDW]: k-major, a inner

    const size_t mem_base = ((size_t)b * T_ + t0) * DE;

    // ---- phase 3: main GEMM over K=512 ----
    for (int kc = 0; kc < DE / KC; ++kc) {
        const int k0 = kc * KC;
#pragma unroll
        for (int r = 0; r < 4; ++r) {
            int u = tid + 256 * r;
            int t = u >> 3;
            int kq = (u & 7) * 4;
            float4 v = *(const float4*)(mem + mem_base + (size_t)t * DE + k0 + kq);
            As[(kq + 0) * LDW + t] = v.x;
            As[(kq + 1) * LDW + t] = v.y;
            As[(kq + 2) * LDW + t] = v.z;
            As[(kq + 3) * LDW + t] = v.w;
        }
#pragma unroll
        for (int r = 0; r < 4; ++r) {
            int u = tid + 256 * r;
            int a = u >> 3;
            int kq = (u & 7) * 4;
            float4 v = *(const float4*)(Wm + (size_t)a * DE + k0 + kq);
            Bs[(kq + 0) * LDW + a] = v.x;
            Bs[(kq + 1) * LDW + a] = v.y;
            Bs[(kq + 2) * LDW + a] = v.z;
            Bs[(kq + 3) * LDW + a] = v.w;
        }
        __syncthreads();
#pragma unroll 8
        for (int k = 0; k < KC; ++k) {
            float4 a0 = *(const float4*)(As + k * LDW + ty * 8);
            float4 a1 = *(const float4*)(As + k * LDW + ty * 8 + 4);
            float4 b0 = *(const float4*)(Bs + k * LDW + tx * 8);
            float4 b1 = *(const float4*)(Bs + k * LDW + tx * 8 + 4);
            float av[8] = {a0.x, a0.y, a0.z, a0.w, a1.x, a1.y, a1.z, a1.w};
            float bw[8] = {b0.x, b0.y, b0.z, b0.w, b1.x, b1.y, b1.z, b1.w};
#pragma unroll
            for (int i = 0; i < 8; ++i)
#pragma unroll
                for (int j = 0; j < 8; ++j) acc[i][j] += av[i] * bw[j];
        }
        __syncthreads();
    }

    // ---- phase 4: location GEMM (K=NF=32) into same accumulators ----
    for (int i = tid; i < NF * DA; i += 256) {
        int f = i >> 7;
        int a = i & 127;
        As[f * LDW + a] = Wloc[(size_t)a * NF + f];  // WlocT[f][a]
    }
    __syncthreads();
#pragma unroll 8
    for (int f = 0; f < NF; ++f) {
        float4 a0 = *(const float4*)(convT + f * LDW + ty * 8);
        float4 a1 = *(const float4*)(convT + f * LDW + ty * 8 + 4);
        float4 b0 = *(const float4*)(As + f * LDW + tx * 8);
        float4 b1 = *(const float4*)(As + f * LDW + tx * 8 + 4);
        float av[8] = {a0.x, a0.y, a0.z, a0.w, a1.x, a1.y, a1.z, a1.w};
        float bw[8] = {b0.x, b0.y, b0.z, b0.w, b1.x, b1.y, b1.z, b1.w};
#pragma unroll
        for (int i = 0; i < 8; ++i)
#pragma unroll
            for (int j = 0; j < 8; ++j) acc[i][j] += av[i] * bw[j];
    }

    // ---- phase 5: tanh, Wv-weighted reduce over a ----
    float res[8];
#pragma unroll
    for (int i = 0; i < 8; ++i) res[i] = 0.f;
#pragma unroll
    for (int j = 0; j < 8; ++j) {
        int a = tx * 8 + j;
        float qb = qb_s[a];
        float wv = wv_s[a];
#pragma unroll
        for (int i = 0; i < 8; ++i) {
            res[i] += wv * tanhf(acc[i][j] + qb);
        }
    }
    float bvv = bv[0];
#pragma unroll
    for (int i = 0; i < 8; ++i) {
        float v = res[i];
        v += __shfl_xor(v, 1, 64);
        v += __shfl_xor(v, 2, 64);
        v += __shfl_xor(v, 4, 64);
        v += __shfl_xor(v, 8, 64);
        if (tx == 0) e_out[(size_t)b * T_ + t0 + ty * 8 + i] = v + bvv;
    }
}

// ---------------- Kernel 3: softmax over T per b ----------------
__global__ __launch_bounds__(256) void softmax_kernel(const float* __restrict__ e,
                                                      float* __restrict__ wout) {
    int b = blockIdx.x;
    int tid = threadIdx.x;
    __shared__ float red[4];
    float v[8];
    float m = -1e30f;
#pragma unroll
    for (int r = 0; r < 8; ++r) {
        v[r] = e[(size_t)b * T_ + r * 256 + tid];
        m = fmaxf(m, v[r]);
    }
#pragma unroll
    for (int off = 1; off < 64; off <<= 1) m = fmaxf(m, __shfl_xor(m, off, 64));
    if ((tid & 63) == 0) red[tid >> 6] = m;
    __syncthreads();
    m = fmaxf(fmaxf(red[0], red[1]), fmaxf(red[2], red[3]));
    __syncthreads();
    float s = 0.f;
#pragma unroll
    for (int r = 0; r < 8; ++r) {
        v[r] = expf(v[r] - m);
        s += v[r];
    }
#pragma unroll
    for (int off = 1; off < 64; off <<= 1) s += __shfl_xor(s, off, 64);
    if ((tid & 63) == 0) red[tid >> 6] = s;
    __syncthreads();
    s = red[0] + red[1] + red[2] + red[3];
    float inv = 1.0f / s;
#pragma unroll
    for (int r = 0; r < 8; ++r) wout[(size_t)b * T_ + r * 256 + tid] = v[r] * inv;
}

// ---------------- Kernel 4: context partials over T chunks ----------------
#define CT 128
__global__ __launch_bounds__(256) void ctx_partial_kernel(const float* __restrict__ mem,
                                                          const float* __restrict__ w,
                                                          float* __restrict__ partial) {
    int b = blockIdx.y;
    int tc = blockIdx.x;  // 0..15
    int tid = threadIdx.x;
    __shared__ float ws_s[CT];
    if (tid < CT) ws_s[tid] = w[(size_t)b * T_ + tc * CT + tid];
    __syncthreads();
    const float* mp = mem + ((size_t)b * T_ + (size_t)tc * CT) * DE;
    float a0 = 0.f, a1 = 0.f;
#pragma unroll 4
    for (int t = 0; t < CT; ++t) {
        float wv = ws_s[t];
        a0 += wv * mp[(size_t)t * DE + tid];
        a1 += wv * mp[(size_t)t * DE + 256 + tid];
    }
    float* pp = partial + ((size_t)b * 16 + tc) * DE;
    pp[tid] = a0;
    pp[tid + 256] = a1;
}

// ---------------- Kernel 5: reduce partials -> context ----------------
__global__ __launch_bounds__(512) void ctx_reduce_kernel(const float* __restrict__ partial,
                                                         float* __restrict__ ctx) {
    int b = blockIdx.x;
    int d = threadIdx.x;
    float s = 0.f;
#pragma unroll
    for (int j = 0; j < 16; ++j) s += partial[((size_t)b * 16 + j) * DE + d];
    ctx[(size_t)b * DE + d] = s;
}

extern "C" void kernel_launch(void* const* d_in, const int* in_sizes, int n_in,
                              void* d_out, int out_size, void* d_ws, size_t ws_size,
                              hipStream_t stream) {
    const float* query  = (const float*)d_in[0];
    const float* memory = (const float*)d_in[1];
    const float* attw   = (const float*)d_in[2];
    const float* Wq     = (const float*)d_in[3];
    const float* bq     = (const float*)d_in[4];
    const float* Wm     = (const float*)d_in[5];
    const float* bm     = (const float*)d_in[6];
    const float* Wconv  = (const float*)d_in[7];
    const float* Wloc   = (const float*)d_in[8];
    const float* Wv     = (const float*)d_in[9];
    const float* bv     = (const float*)d_in[10];

    float* out = (float*)d_out;
    float* ctx_out = out;            // [64,512]  (output 0)
    float* w_out = out + B_ * DE;    // [64,2048] (output 1)

    float* ws = (float*)d_ws;
    float* qbuf = ws;                        // 8192 floats
    float* ebuf = qbuf + B_ * DA;            // 131072 floats
    float* partial = ebuf + (size_t)B_ * T_; // 64*16*512 = 524288 floats

    q_kernel<<<dim3(B_), dim3(128), 0, stream>>>(query, Wq, bq, qbuf);
    energy_kernel<<<dim3(T_ / TT, B_), dim3(256), 0, stream>>>(
        memory, attw, Wm, bm, Wconv, Wloc, Wv, bv, qbuf, ebuf);
    softmax_kernel<<<dim3(B_), dim3(256), 0, stream>>>(ebuf, w_out);
    ctx_partial_kernel<<<dim3(16, B_), dim3(256), 0, stream>>>(memory, w_out, partial);
    ctx_reduce_kernel<<<dim3(B_), dim3(512), 0, stream>>>(partial, ctx_out);
}

// Round 2
// 540.922 us; speedup vs baseline: 1.2337x; 1.2337x over previous
//
#include <hip/hip_runtime.h>
#include <math.h>

#define B_ 64
#define T_ 2048
#define DL 1024
#define DE 512
#define DA 128
#define NF 32
#define KW 31
#define PADW 15
#define TT 128
#define LDA 40   // bf16 LDS row stride: 32 cols + 8 pad (80 B, breaks pow2 banking)

typedef short bf16x8 __attribute__((ext_vector_type(8)));
typedef float f32x4 __attribute__((ext_vector_type(4)));

// split fp32 into bf16 hi + bf16 lo (RNE), x ~= hi + lo to ~2^-17 rel
__device__ __forceinline__ void split_bf16(float x, unsigned short &hi, unsigned short &lo) {
    unsigned u = __float_as_uint(x);
    unsigned short h = (unsigned short)((u + 0x7FFFu + ((u >> 16) & 1u)) >> 16);
    float hf = __uint_as_float((unsigned)h << 16);
    float l = x - hf;
    unsigned ul = __float_as_uint(l);
    hi = h;
    lo = (unsigned short)((ul + 0x7FFFu + ((ul >> 16) & 1u)) >> 16);
}

__device__ __forceinline__ float fast_tanh(float x) {
    x = fminf(fmaxf(x, -15.f), 15.f);
    float e2 = __expf(2.f * x);
    return (e2 - 1.f) * __builtin_amdgcn_rcpf(e2 + 1.f);
}

// ---------------- prep: split Wm into bf16 hi/lo [128][512] ----------------
__global__ __launch_bounds__(256) void prep_kernel(const float* __restrict__ Wm,
                                                   unsigned short* __restrict__ bg_hi,
                                                   unsigned short* __restrict__ bg_lo) {
    int i = blockIdx.x * 256 + threadIdx.x;  // 65536 elements
    unsigned short h, l;
    split_bf16(Wm[i], h, l);
    bg_hi[i] = h;
    bg_lo[i] = l;
}

// ---------------- q = query @ Wq.T + bq  ([B,128]) ----------------
__global__ __launch_bounds__(128) void q_kernel(const float* __restrict__ query,
                                                const float* __restrict__ Wq,
                                                const float* __restrict__ bq,
                                                float* __restrict__ qbuf) {
    int b = blockIdx.x;
    int a = threadIdx.x;
    __shared__ __align__(16) float qs[DL];
    for (int i = threadIdx.x; i < DL; i += 128) qs[i] = query[(size_t)b * DL + i];
    __syncthreads();
    const float* wrow = Wq + (size_t)a * DL;
    float acc = 0.f;
#pragma unroll 8
    for (int i = 0; i < DL; i += 4) {
        float4 w = *(const float4*)(wrow + i);
        float4 q4 = *(const float4*)(qs + i);
        acc += w.x * q4.x + w.y * q4.y + w.z * q4.z + w.w * q4.w;
    }
    qbuf[(size_t)b * DA + a] = acc + bq[a];
}

// ---------------- energies via split-bf16 MFMA ----------------
// Block: (t-tile of 128) x (all 128 a), b = blockIdx.y. 4 waves in 2x2.
// acc[t][a] = sum_k mem*Wm (K=512) + sum_f conv*Wloc (K=32, chunk -1)
// e[b,t] = bv + sum_a Wv[a]*tanh(acc + q[b,a] + bm[a])
__global__ __launch_bounds__(256, 3) void energy_kernel(
    const float* __restrict__ mem,            // [B,T,512]
    const float* __restrict__ attw,           // [B,2,T]
    const unsigned short* __restrict__ bg_hi, // Wm hi bf16 [128][512]
    const unsigned short* __restrict__ bg_lo, // Wm lo bf16 [128][512]
    const float* __restrict__ bm,
    const float* __restrict__ Wconv,          // [32,2,31]
    const float* __restrict__ Wloc,           // [128,32]
    const float* __restrict__ Wv,
    const float* __restrict__ bv,
    const float* __restrict__ qbuf,           // [B,128]
    float* __restrict__ e_out)                // [B,T]
{
    __shared__ __align__(16) unsigned short Ahi[TT * LDA];
    __shared__ __align__(16) unsigned short Alo[TT * LDA];
    __shared__ __align__(16) unsigned short Bhi[DA * LDA];
    __shared__ __align__(16) unsigned short Blo[DA * LDA];
    __shared__ __align__(16) float attw_s[2 * 160];
    __shared__ __align__(16) float wconv_s[NF * 64];
    __shared__ float qb_s[DA], wv_s[DA];
    __shared__ float e_part[2][TT];

    const int tid = threadIdx.x;
    const int b = blockIdx.y;
    const int t0 = blockIdx.x * TT;
    const int lane = tid & 63;
    const int wave = tid >> 6;
    const int wm = wave & 1, wn = wave >> 1;
    const int m = lane & 15;
    const int q8 = (lane >> 4) * 8;

    if (tid < DA) {
        qb_s[tid] = qbuf[(size_t)b * DA + tid] + bm[tid];
        wv_s[tid] = Wv[tid];
    }

    // stage attw slice + wconv
    for (int i = tid; i < 2 * (TT + KW - 1); i += 256) {
        int c = i / 158, j = i % 158;
        int t = t0 - PADW + j;
        attw_s[c * 160 + j] = (t >= 0 && t < T_) ? attw[((size_t)b * 2 + c) * T_ + t] : 0.f;
    }
    for (int i = tid; i < NF * 2 * KW; i += 256) {
        int f = i / 62, r = i % 62;
        wconv_s[f * 64 + r] = Wconv[i];
    }
    __syncthreads();

    // conv chunk: A <- conv[t][f] split, B <- Wloc[a][f] split (cols 0..31)
    for (int i = tid; i < TT * NF; i += 256) {
        int t = i >> 5, f = i & 31;
        const float* w0 = wconv_s + f * 64;
        const float* a0 = attw_s + t;
        const float* a1 = attw_s + 160 + t;
        float s = 0.f;
#pragma unroll
        for (int k = 0; k < KW; ++k) s += w0[k] * a0[k] + w0[31 + k] * a1[k];
        unsigned short h, l;
        split_bf16(s, h, l);
        Ahi[t * LDA + f] = h;
        Alo[t * LDA + f] = l;
    }
    for (int i = tid; i < DA * NF; i += 256) {
        int a = i >> 5, f = i & 31;
        unsigned short h, l;
        split_bf16(Wloc[a * NF + f], h, l);
        Bhi[a * LDA + f] = h;
        Blo[a * LDA + f] = l;
    }
    __syncthreads();

    f32x4 acc[4][4];
#pragma unroll
    for (int mi = 0; mi < 4; ++mi)
#pragma unroll
        for (int ni = 0; ni < 4; ++ni) {
            f32x4 z = {0.f, 0.f, 0.f, 0.f};
            acc[mi][ni] = z;
        }

    auto mfma_step = [&]() {
        bf16x8 ah[4], al[4];
#pragma unroll
        for (int mi = 0; mi < 4; ++mi) {
            int r = (wm * 64 + mi * 16 + m) * LDA + q8;
            ah[mi] = *(const bf16x8*)(Ahi + r);
            al[mi] = *(const bf16x8*)(Alo + r);
        }
#pragma unroll
        for (int ni = 0; ni < 4; ++ni) {
            int r = (wn * 64 + ni * 16 + m) * LDA + q8;
            bf16x8 bh = *(const bf16x8*)(Bhi + r);
            bf16x8 bl = *(const bf16x8*)(Blo + r);
#pragma unroll
            for (int mi = 0; mi < 4; ++mi) {
                acc[mi][ni] = __builtin_amdgcn_mfma_f32_16x16x32_bf16(ah[mi], bh, acc[mi][ni], 0, 0, 0);
                acc[mi][ni] = __builtin_amdgcn_mfma_f32_16x16x32_bf16(ah[mi], bl, acc[mi][ni], 0, 0, 0);
                acc[mi][ni] = __builtin_amdgcn_mfma_f32_16x16x32_bf16(al[mi], bh, acc[mi][ni], 0, 0, 0);
            }
        }
    };

    mfma_step();  // conv/location chunk

    const size_t mem_base = ((size_t)b * T_ + t0) * DE;
    for (int c = 0; c < 16; ++c) {
        const int k0 = c * 32;
        __syncthreads();  // MFMA reads of previous chunk done
#pragma unroll
        for (int r = 0; r < 4; ++r) {
            int idx = tid + 256 * r;
            int t = idx >> 3, c4 = (idx & 7) * 4;
            float4 v = *(const float4*)(mem + mem_base + (size_t)t * DE + k0 + c4);
            unsigned short h0, l0, h1, l1, h2, l2, h3, l3;
            split_bf16(v.x, h0, l0);
            split_bf16(v.y, h1, l1);
            split_bf16(v.z, h2, l2);
            split_bf16(v.w, h3, l3);
            ushort4 hv = {h0, h1, h2, h3};
            ushort4 lv = {l0, l1, l2, l3};
            *(ushort4*)(Ahi + t * LDA + c4) = hv;
            *(ushort4*)(Alo + t * LDA + c4) = lv;
        }
#pragma unroll
        for (int r = 0; r < 2; ++r) {
            int idx = tid + 256 * r;
            int a = idx >> 2, c8 = (idx & 3) * 8;
            *(uint4*)(Bhi + a * LDA + c8) = *(const uint4*)(bg_hi + (size_t)a * DE + k0 + c8);
            *(uint4*)(Blo + a * LDA + c8) = *(const uint4*)(bg_lo + (size_t)a * DE + k0 + c8);
        }
        __syncthreads();
        mfma_step();
    }

    // epilogue: e[t] = bv + sum_a wv[a]*tanh(acc + qb[a])
    float wvr[4], qbr[4];
#pragma unroll
    for (int ni = 0; ni < 4; ++ni) {
        int a = wn * 64 + ni * 16 + m;
        wvr[ni] = wv_s[a];
        qbr[ni] = qb_s[a];
    }
    float bvv = bv[0];
#pragma unroll
    for (int mi = 0; mi < 4; ++mi) {
#pragma unroll
        for (int reg = 0; reg < 4; ++reg) {
            float s = 0.f;
#pragma unroll
            for (int ni = 0; ni < 4; ++ni)
                s += wvr[ni] * fast_tanh(acc[mi][ni][reg] + qbr[ni]);
            s += __shfl_xor(s, 1, 64);
            s += __shfl_xor(s, 2, 64);
            s += __shfl_xor(s, 4, 64);
            s += __shfl_xor(s, 8, 64);
            if (m == 0)
                e_part[wn][wm * 64 + mi * 16 + (lane >> 4) * 4 + reg] = s;
        }
    }
    __syncthreads();
    if (tid < TT)
        e_out[(size_t)b * T_ + t0 + tid] = e_part[0][tid] + e_part[1][tid] + bvv;
}

// ---------------- softmax over T per b ----------------
__global__ __launch_bounds__(256) void softmax_kernel(const float* __restrict__ e,
                                                      float* __restrict__ wout) {
    int b = blockIdx.x;
    int tid = threadIdx.x;
    __shared__ float red[4];
    float v[8];
    float m = -1e30f;
#pragma unroll
    for (int r = 0; r < 8; ++r) {
        v[r] = e[(size_t)b * T_ + r * 256 + tid];
        m = fmaxf(m, v[r]);
    }
#pragma unroll
    for (int off = 1; off < 64; off <<= 1) m = fmaxf(m, __shfl_xor(m, off, 64));
    if ((tid & 63) == 0) red[tid >> 6] = m;
    __syncthreads();
    m = fmaxf(fmaxf(red[0], red[1]), fmaxf(red[2], red[3]));
    __syncthreads();
    float s = 0.f;
#pragma unroll
    for (int r = 0; r < 8; ++r) {
        v[r] = expf(v[r] - m);
        s += v[r];
    }
#pragma unroll
    for (int off = 1; off < 64; off <<= 1) s += __shfl_xor(s, off, 64);
    if ((tid & 63) == 0) red[tid >> 6] = s;
    __syncthreads();
    s = red[0] + red[1] + red[2] + red[3];
    float inv = 1.0f / s;
#pragma unroll
    for (int r = 0; r < 8; ++r) wout[(size_t)b * T_ + r * 256 + tid] = v[r] * inv;
}

// ---------------- context partials (float4) ----------------
__global__ __launch_bounds__(256) void ctx_partial_kernel(const float* __restrict__ mem,
                                                          const float* __restrict__ w,
                                                          float* __restrict__ partial) {
    int b = blockIdx.y, tc = blockIdx.x;  // 16 chunks of 128 t
    int tid = threadIdx.x;
    __shared__ float ws_s[128];
    __shared__ float red[512];
    if (tid < 128) ws_s[tid] = w[(size_t)b * T_ + tc * 128 + tid];
    __syncthreads();
    int d = (tid & 127) * 4;
    int th = tid >> 7;  // two t-halves of 64
    const float* mp = mem + ((size_t)b * T_ + tc * 128 + th * 64) * DE + d;
    float a0 = 0.f, a1 = 0.f, a2 = 0.f, a3 = 0.f;
#pragma unroll 8
    for (int t = 0; t < 64; ++t) {
        float4 v = *(const float4*)(mp + (size_t)t * DE);
        float wv = ws_s[th * 64 + t];
        a0 += wv * v.x; a1 += wv * v.y; a2 += wv * v.z; a3 += wv * v.w;
    }
    if (th == 1) {
        float* r = red + (tid & 127) * 4;
        r[0] = a0; r[1] = a1; r[2] = a2; r[3] = a3;
    }
    __syncthreads();
    if (th == 0) {
        const float* r = red + tid * 4;
        float* pp = partial + ((size_t)b * 16 + tc) * DE + d;
        pp[0] = a0 + r[0]; pp[1] = a1 + r[1]; pp[2] = a2 + r[2]; pp[3] = a3 + r[3];
    }
}

// ---------------- reduce partials -> context ----------------
__global__ __launch_bounds__(512) void ctx_reduce_kernel(const float* __restrict__ partial,
                                                         float* __restrict__ ctx) {
    int b = blockIdx.x;
    int d = threadIdx.x;
    float s = 0.f;
#pragma unroll
    for (int j = 0; j < 16; ++j) s += partial[((size_t)b * 16 + j) * DE + d];
    ctx[(size_t)b * DE + d] = s;
}

extern "C" void kernel_launch(void* const* d_in, const int* in_sizes, int n_in,
                              void* d_out, int out_size, void* d_ws, size_t ws_size,
                              hipStream_t stream) {
    const float* query  = (const float*)d_in[0];
    const float* memory = (const float*)d_in[1];
    const float* attw   = (const float*)d_in[2];
    const float* Wq     = (const float*)d_in[3];
    const float* bq     = (const float*)d_in[4];
    const float* Wm     = (const float*)d_in[5];
    const float* bm     = (const float*)d_in[6];
    const float* Wconv  = (const float*)d_in[7];
    const float* Wloc   = (const float*)d_in[8];
    const float* Wv     = (const float*)d_in[9];
    const float* bv     = (const float*)d_in[10];

    float* out = (float*)d_out;
    float* ctx_out = out;          // [64,512]
    float* w_out = out + B_ * DE;  // [64,2048]

    float* ws = (float*)d_ws;
    float* qbuf = ws;                         // 8192 f
    float* ebuf = qbuf + B_ * DA;             // 131072 f
    float* partial = ebuf + (size_t)B_ * T_;  // 524288 f
    unsigned short* bg_hi = (unsigned short*)(partial + (size_t)B_ * 16 * DE);
    unsigned short* bg_lo = bg_hi + DA * DE;

    prep_kernel<<<dim3(DA * DE / 256), dim3(256), 0, stream>>>(Wm, bg_hi, bg_lo);
    q_kernel<<<dim3(B_), dim3(128), 0, stream>>>(query, Wq, bq, qbuf);
    energy_kernel<<<dim3(T_ / TT, B_), dim3(256), 0, stream>>>(
        memory, attw, bg_hi, bg_lo, bm, Wconv, Wloc, Wv, bv, qbuf, ebuf);
    softmax_kernel<<<dim3(B_), dim3(256), 0, stream>>>(ebuf, w_out);
    ctx_partial_kernel<<<dim3(16, B_), dim3(256), 0, stream>>>(memory, w_out, partial);
    ctx_reduce_kernel<<<dim3(B_), dim3(512), 0, stream>>>(partial, ctx_out);
}